// Round 2
// baseline (1387.643 us; speedup 1.0000x reference)
//
#include <hip/hip_runtime.h>

#define DEVINL __device__ __forceinline__

typedef __attribute__((ext_vector_type(8))) short s16x8;
typedef __attribute__((ext_vector_type(4))) float f32x4;

DEVINL unsigned short f2bf(float f) {
  union { float f; unsigned u; } v; v.f = f;
  unsigned r = v.u + 0x7FFFu + ((v.u >> 16) & 1u);
  return (unsigned short)(r >> 16);
}

DEVINL float wave_sum(float v) {
#pragma unroll
  for (int o = 32; o > 0; o >>= 1) v += __shfl_xor(v, o, 64);
  return v;
}
DEVINL float wave_max(float v) {
#pragma unroll
  for (int o = 32; o > 0; o >>= 1) v = fmaxf(v, __shfl_xor(v, o, 64));
  return v;
}

// ---------------- weight prep: fp32 -> bf16, stack wq|wk ----------------
__global__ __launch_bounds__(256) void prep_kernel(
    const float* __restrict__ wq, const float* __restrict__ wk,
    const float* __restrict__ wv, const float* __restrict__ wo,
    const float* __restrict__ bq, const float* __restrict__ bk,
    unsigned short* __restrict__ wqk, unsigned short* __restrict__ wvb,
    unsigned short* __restrict__ wob, float* __restrict__ bqk) {
  int i = blockIdx.x * 256 + threadIdx.x;      // grid = 1024 blocks -> 262144
  wqk[i]          = f2bf(wq[i]);
  wqk[262144 + i] = f2bf(wk[i]);
  wvb[i] = f2bf(wv[i]);
  wob[i] = f2bf(wo[i]);
  if (i < 512) { bqk[i] = bq[i]; bqk[512 + i] = bk[i]; }
}

// ---------------- GroupNorm stats: one block per (b,g) ----------------
__global__ __launch_bounds__(256) void gn_stats_kernel(
    const float* __restrict__ x, float* __restrict__ stats) {
  int bg = blockIdx.x;                          // 0..255 (b*32+g)
  const float4* p = (const float4*)(x + (long)bg * 65536);
  float s = 0.f, ss = 0.f;
#pragma unroll 8
  for (int i = 0; i < 64; ++i) {
    float4 v = p[threadIdx.x + 256 * i];
    s  += v.x + v.y + v.z + v.w;
    ss += v.x*v.x + v.y*v.y + v.z*v.z + v.w*v.w;
  }
  __shared__ float red[8];
  float w1 = wave_sum(s), w2 = wave_sum(ss);
  int wave = threadIdx.x >> 6;
  if ((threadIdx.x & 63) == 0) { red[wave] = w1; red[4 + wave] = w2; }
  __syncthreads();
  if (threadIdx.x == 0) {
    float S1 = red[0] + red[1] + red[2] + red[3];
    float S2 = red[4] + red[5] + red[6] + red[7];
    float mu = S1 * (1.f / 65536.f);
    float var = S2 * (1.f / 65536.f) - mu * mu;
    stats[bg * 2]     = mu;
    stats[bg * 2 + 1] = rsqrtf(var + 1e-5f);
  }
}

// ------- GroupNorm normalize + transpose: hb[blockIdx.y][n][c] bf16 ------
__global__ __launch_bounds__(256) void gn_norm_kernel(
    const float* __restrict__ x, const float* __restrict__ stats,
    const float* __restrict__ gamma, const float* __restrict__ beta,
    unsigned short* __restrict__ hout, int b0) {
  int b = b0 + blockIdx.y;                      // real batch index
  int n0 = blockIdx.x * 128;
  int tid = threadIdx.x;
  __shared__ unsigned short lt[128][33];
  const float* xb = x + (long)b * (512L * 4096);
  unsigned short* hb = hout + (long)blockIdx.y * (4096L * 512);
  for (int cc0 = 0; cc0 < 512; cc0 += 32) {
#pragma unroll
    for (int i = 0; i < 4; ++i) {
      int idx = tid + 256 * i;                 // [0,1024) float4s of 32c x 128n
      int c = idx >> 5, nf = idx & 31;
      int ch = cc0 + c;
      float4 v = *(const float4*)(xb + (long)ch * 4096 + n0 + nf * 4);
      float mu = stats[(b * 32 + (ch >> 4)) * 2];
      float rs = stats[(b * 32 + (ch >> 4)) * 2 + 1];
      float ga = gamma[ch] * rs;
      float be = beta[ch] - mu * ga;
      int nl = nf * 4;
      lt[nl + 0][c] = f2bf(v.x * ga + be);
      lt[nl + 1][c] = f2bf(v.y * ga + be);
      lt[nl + 2][c] = f2bf(v.z * ga + be);
      lt[nl + 3][c] = f2bf(v.w * ga + be);
    }
    __syncthreads();
#pragma unroll
    for (int i = 0; i < 2; ++i) {
      int idx = tid + 256 * i;                 // [0,512) uint4 stores
      int row = idx >> 2, part = idx & 3;
      union { uint4 u; unsigned short s[8]; } o;
#pragma unroll
      for (int j = 0; j < 8; ++j) o.s[j] = lt[row][part * 8 + j];
      *(uint4*)(hb + (long)(n0 + row) * 512 + cc0 + part * 8) = o.u;
    }
    __syncthreads();
  }
}

// ---------------- NT GEMM: Out[i][j] = sum_k A[i][k]*B[j][k] -------------
#define BM 128
#define BN 128
#define BKD 64

enum { EPI_BF16 = 0, EPI_BF16_COLBIAS = 1, EPI_BF16_ROWBIAS = 2,
       EPI_F32_SCALE = 3, EPI_F32_RES = 4 };

DEVINL void stage128x64(const unsigned short* g, int ld, unsigned short* l, int tid) {
  int wave = tid >> 6;
#pragma unroll
  for (int it = 0; it < 4; ++it) {
    int seg = it * 256 + tid;                  // [0,1024): 16B segments
    int row = seg >> 3, ks = seg & 7;
    const unsigned short* gp = g + (long)row * ld + ks * 8;
    unsigned short* lp = l + (it * 256 + wave * 64) * 8;   // wave-uniform base
    __builtin_amdgcn_global_load_lds(
        (const __attribute__((address_space(1))) void*)gp,
        (__attribute__((address_space(3))) void*)lp, 16, 0, 0);
  }
}

template <int EPI>
__global__ __launch_bounds__(256, 2) void gemm_nt(
    const unsigned short* __restrict__ A, long strideA, int lda,
    const unsigned short* __restrict__ B, long strideB, int ldb,
    void* __restrict__ C, long strideC, int ldc, int K,
    const float* __restrict__ bias, float scale,
    const float* __restrict__ resid, long strideR) {
  __shared__ __align__(16) unsigned short lA[BM * BKD];
  __shared__ __align__(16) unsigned short lB[BN * BKD];
  int z = blockIdx.z;
  const unsigned short* Ab = A + (long)z * strideA + (long)blockIdx.y * BM * lda;
  const unsigned short* Bb = B + (long)z * strideB + (long)blockIdx.x * BN * ldb;
  int tid = threadIdx.x;
  int lane = tid & 63, wave = tid >> 6;
  int wm = (wave >> 1) * 64, wn = (wave & 1) * 64;
  int lr = lane & 15;
  int lk = (lane >> 4) * 8;

  f32x4 acc[4][4];
#pragma unroll
  for (int i = 0; i < 4; ++i)
#pragma unroll
    for (int j = 0; j < 4; ++j) acc[i][j] = (f32x4){0.f, 0.f, 0.f, 0.f};

  for (int k0 = 0; k0 < K; k0 += BKD) {
    __syncthreads();
    stage128x64(Ab + k0, lda, lA, tid);
    stage128x64(Bb + k0, ldb, lB, tid);
    __syncthreads();
#pragma unroll
    for (int kk = 0; kk < 2; ++kk) {
      s16x8 af[4], bfr[4];
#pragma unroll
      for (int i = 0; i < 4; ++i)
        af[i] = *(const s16x8*)&lA[(wm + i * 16 + lr) * BKD + kk * 32 + lk];
#pragma unroll
      for (int i = 0; i < 4; ++i)
        bfr[i] = *(const s16x8*)&lB[(wn + i * 16 + lr) * BKD + kk * 32 + lk];
#pragma unroll
      for (int mi = 0; mi < 4; ++mi)
#pragma unroll
        for (int ni = 0; ni < 4; ++ni)
          acc[mi][ni] = __builtin_amdgcn_mfma_f32_16x16x32_bf16(
              af[mi], bfr[ni], acc[mi][ni], 0, 0, 0);
    }
  }

  int rbase = blockIdx.y * BM + wm + (lane >> 4) * 4;
  int cbase = blockIdx.x * BN + wn + lr;
  long cb = (long)z * strideC;
#pragma unroll
  for (int mi = 0; mi < 4; ++mi) {
#pragma unroll
    for (int ni = 0; ni < 4; ++ni) {
      int col = cbase + ni * 16;
#pragma unroll
      for (int r = 0; r < 4; ++r) {
        int row = rbase + mi * 16 + r;
        float val = acc[mi][ni][r];
        long off = cb + (long)row * ldc + col;
        if constexpr (EPI == EPI_BF16) {
          ((unsigned short*)C)[off] = f2bf(val);
        } else if constexpr (EPI == EPI_BF16_COLBIAS) {
          ((unsigned short*)C)[off] = f2bf(val + bias[col]);
        } else if constexpr (EPI == EPI_BF16_ROWBIAS) {
          ((unsigned short*)C)[off] = f2bf(val + bias[row]);
        } else if constexpr (EPI == EPI_F32_SCALE) {
          ((float*)C)[off] = val * scale;
        } else {
          ((float*)C)[off] =
              val + bias[row] + resid[(long)z * strideR + (long)row * ldc + col];
        }
      }
    }
  }
}

// ---------------- row softmax: S fp32 [4096] -> P bf16 ----------------
__global__ __launch_bounds__(256) void softmax_kernel(
    const float* __restrict__ S, unsigned short* __restrict__ P) {
  __shared__ float red[4];
  long row = blockIdx.x;
  const float4* s = (const float4*)(S + row * 4096);
  int tid = threadIdx.x;
  float4 v[4];
  float m = -3e38f;
#pragma unroll
  for (int i = 0; i < 4; ++i) {
    v[i] = s[tid + 256 * i];
    m = fmaxf(m, fmaxf(fmaxf(v[i].x, v[i].y), fmaxf(v[i].z, v[i].w)));
  }
  m = wave_max(m);
  if ((tid & 63) == 0) red[tid >> 6] = m;
  __syncthreads();
  m = fmaxf(fmaxf(red[0], red[1]), fmaxf(red[2], red[3]));
  __syncthreads();
  float sum = 0.f;
#pragma unroll
  for (int i = 0; i < 4; ++i) {
    v[i].x = __expf(v[i].x - m); v[i].y = __expf(v[i].y - m);
    v[i].z = __expf(v[i].z - m); v[i].w = __expf(v[i].w - m);
    sum += v[i].x + v[i].y + v[i].z + v[i].w;
  }
  sum = wave_sum(sum);
  if ((tid & 63) == 0) red[tid >> 6] = sum;
  __syncthreads();
  sum = red[0] + red[1] + red[2] + red[3];
  float inv = 1.f / sum;
  ushort4* pp = (ushort4*)(P + row * 4096);
#pragma unroll
  for (int i = 0; i < 4; ++i) {
    ushort4 o;
    o.x = f2bf(v[i].x * inv); o.y = f2bf(v[i].y * inv);
    o.z = f2bf(v[i].z * inv); o.w = f2bf(v[i].w * inv);
    pp[tid + 256 * i] = o;
  }
}

// ---------------- launcher (workspace-adaptive) ----------------
extern "C" void kernel_launch(void* const* d_in, const int* in_sizes, int n_in,
                              void* d_out, int out_size, void* d_ws, size_t ws_size,
                              hipStream_t stream) {
  const float* x   = (const float*)d_in[0];
  const float* gsc = (const float*)d_in[1];
  const float* gbi = (const float*)d_in[2];
  const float* wq  = (const float*)d_in[3];
  const float* bq  = (const float*)d_in[4];
  const float* wk  = (const float*)d_in[5];
  const float* bk  = (const float*)d_in[6];
  const float* wv  = (const float*)d_in[7];
  const float* bv  = (const float*)d_in[8];
  const float* wo  = (const float*)d_in[9];
  const float* bo  = (const float*)d_in[10];
  float* out = (float*)d_out;

  // small fixed region (~2.1 MB) at the start
  char* w = (char*)d_ws;
  unsigned short* wqk  = (unsigned short*)(w);             // 1,048,576 B
  unsigned short* wvb  = (unsigned short*)(w + 1048576);   //   524,288 B
  unsigned short* wob  = (unsigned short*)(w + 1572864);   //   524,288 B
  float*          bqk  = (float*)(w + 2097152);            //     4,096 B
  float*          stats= (float*)(w + 2101248);            //     2,048 B
  char* big = w + 4194304;                                 // big buffers at 4 MiB
  size_t avail = ws_size > 4194304 ? ws_size - 4194304 : 0;

  prep_kernel<<<1024, 256, 0, stream>>>(wq, wk, wv, wo, bq, bk, wqk, wvb, wob, bqk);
  gn_stats_kernel<<<256, 256, 0, stream>>>(x, stats);

  const float scale = 0.04419417382415922f;   // 512^-0.5
  const long HB = 4096L * 512;                // per-batch h/o elements
  const long XB = 512L * 4096;                // per-batch x/out elements

  if (avail >= 209715200) {
    // ---- tier 1: batched GN / V-proj / out-proj; per-batch qk + S/P ----
    unsigned short* h_t = (unsigned short*)(big);              // 33,554,432
    unsigned short* qk  = (unsigned short*)(big + 33554432);   //  8,388,608
    unsigned short* vb  = (unsigned short*)(big + 41943040);   // 33,554,432
    unsigned short* o_t = (unsigned short*)(big + 75497472);   // 33,554,432
    float*          S   = (float*)(big + 109051904);           // 67,108,864
    unsigned short* P   = (unsigned short*)(big + 176160768);  // 33,554,432

    gn_norm_kernel<<<dim3(32, 8), 256, 0, stream>>>(x, stats, gsc, gbi, h_t, 0);
    gemm_nt<EPI_BF16_ROWBIAS><<<dim3(32, 4, 8), 256, 0, stream>>>(
        wvb, 0, 512, h_t, HB, 512, vb, XB, 4096, 512, bv, 1.f, nullptr, 0);
    for (int b = 0; b < 8; ++b) {
      gemm_nt<EPI_BF16_COLBIAS><<<dim3(8, 32, 1), 256, 0, stream>>>(
          h_t + b * HB, 0, 512, wqk, 0, 512, qk, 0, 1024, 512, bqk, 1.f, nullptr, 0);
      gemm_nt<EPI_F32_SCALE><<<dim3(32, 32, 1), 256, 0, stream>>>(
          qk, 0, 1024, qk + 512, 0, 1024, S, 0, 4096, 512, nullptr, scale, nullptr, 0);
      softmax_kernel<<<4096, 256, 0, stream>>>(S, P);
      gemm_nt<EPI_BF16><<<dim3(4, 32, 1), 256, 0, stream>>>(
          P, 0, 4096, vb + b * XB, 0, 4096, o_t + b * HB, 0, 512, 4096,
          nullptr, 1.f, nullptr, 0);
    }
    gemm_nt<EPI_F32_RES><<<dim3(32, 4, 8), 256, 0, stream>>>(
        wob, 0, 512, o_t, HB, 512, out, XB, 4096, 512, bo, 1.f, x, XB);

  } else if (avail >= 121634816) {
    // ---- tier 2: everything per batch, full-size fp32 S ----
    unsigned short* h_b = (unsigned short*)(big);              //  4,194,304
    unsigned short* qk  = (unsigned short*)(big + 4194304);    //  8,388,608
    unsigned short* v_b = (unsigned short*)(big + 12582912);   //  4,194,304
    unsigned short* o_b = (unsigned short*)(big + 16777216);   //  4,194,304
    float*          S   = (float*)(big + 20971520);            // 67,108,864
    unsigned short* P   = (unsigned short*)(big + 88080384);   // 33,554,432

    for (int b = 0; b < 8; ++b) {
      gn_norm_kernel<<<dim3(32, 1), 256, 0, stream>>>(x, stats, gsc, gbi, h_b, b);
      gemm_nt<EPI_BF16_COLBIAS><<<dim3(8, 32, 1), 256, 0, stream>>>(
          h_b, 0, 512, wqk, 0, 512, qk, 0, 1024, 512, bqk, 1.f, nullptr, 0);
      gemm_nt<EPI_BF16_ROWBIAS><<<dim3(32, 4, 1), 256, 0, stream>>>(
          wvb, 0, 512, h_b, 0, 512, v_b, 0, 4096, 512, bv, 1.f, nullptr, 0);
      gemm_nt<EPI_F32_SCALE><<<dim3(32, 32, 1), 256, 0, stream>>>(
          qk, 0, 1024, qk + 512, 0, 1024, S, 0, 4096, 512, nullptr, scale, nullptr, 0);
      softmax_kernel<<<4096, 256, 0, stream>>>(S, P);
      gemm_nt<EPI_BF16><<<dim3(4, 32, 1), 256, 0, stream>>>(
          P, 0, 4096, v_b, 0, 4096, o_b, 0, 512, 4096, nullptr, 1.f, nullptr, 0);
      gemm_nt<EPI_F32_RES><<<dim3(32, 4, 1), 256, 0, stream>>>(
          wob, 0, 512, o_b, 0, 512, out + b * XB, 0, 4096, 512,
          bo, 1.f, x + b * XB, 0);
    }

  } else if (avail >= 46137344) {
    // ---- tier 3: per batch + row-chunked attention (1024 rows) ----
    unsigned short* h_b = (unsigned short*)(big);              //  4,194,304
    unsigned short* qk  = (unsigned short*)(big + 4194304);    //  8,388,608
    unsigned short* v_b = (unsigned short*)(big + 12582912);   //  4,194,304
    unsigned short* o_b = (unsigned short*)(big + 16777216);   //  4,194,304
    float*          Sc  = (float*)(big + 20971520);            // 16,777,216
    unsigned short* Pc  = (unsigned short*)(big + 37748736);   //  8,388,608

    for (int b = 0; b < 8; ++b) {
      gn_norm_kernel<<<dim3(32, 1), 256, 0, stream>>>(x, stats, gsc, gbi, h_b, b);
      gemm_nt<EPI_BF16_COLBIAS><<<dim3(8, 32, 1), 256, 0, stream>>>(
          h_b, 0, 512, wqk, 0, 512, qk, 0, 1024, 512, bqk, 1.f, nullptr, 0);
      gemm_nt<EPI_BF16_ROWBIAS><<<dim3(32, 4, 1), 256, 0, stream>>>(
          wvb, 0, 512, h_b, 0, 512, v_b, 0, 4096, 512, bv, 1.f, nullptr, 0);
      for (int c4 = 0; c4 < 4; ++c4) {
        gemm_nt<EPI_F32_SCALE><<<dim3(32, 8, 1), 256, 0, stream>>>(
            qk + c4 * 1024L * 1024, 0, 1024, qk + 512, 0, 1024,
            Sc, 0, 4096, 512, nullptr, scale, nullptr, 0);
        softmax_kernel<<<1024, 256, 0, stream>>>(Sc, Pc);
        gemm_nt<EPI_BF16><<<dim3(4, 8, 1), 256, 0, stream>>>(
            Pc, 0, 4096, v_b, 0, 4096, o_b + c4 * 1024L * 512, 0, 512, 4096,
            nullptr, 1.f, nullptr, 0);
      }
      gemm_nt<EPI_F32_RES><<<dim3(32, 4, 1), 256, 0, stream>>>(
          wob, 0, 512, o_b, 0, 512, out + b * XB, 0, 4096, 512,
          bo, 1.f, x + b * XB, 0);
    }
  }
  // else: workspace too small — launch nothing (clean diagnostic failure)
}

// Round 3
// 1310.966 us; speedup vs baseline: 1.0585x; 1.0585x over previous
//
#include <hip/hip_runtime.h>

#define DEVINL __device__ __forceinline__

typedef __attribute__((ext_vector_type(8))) short s16x8;
typedef __attribute__((ext_vector_type(4))) float f32x4;

DEVINL unsigned short f2bf(float f) {
  union { float f; unsigned u; } v; v.f = f;
  unsigned r = v.u + 0x7FFFu + ((v.u >> 16) & 1u);
  return (unsigned short)(r >> 16);
}

DEVINL float wave_sum(float v) {
#pragma unroll
  for (int o = 32; o > 0; o >>= 1) v += __shfl_xor(v, o, 64);
  return v;
}

// ---------------- weight prep: fp32 -> bf16, stack wq|wk ----------------
__global__ __launch_bounds__(256) void prep_kernel(
    const float* __restrict__ wq, const float* __restrict__ wk,
    const float* __restrict__ wv, const float* __restrict__ wo,
    const float* __restrict__ bq, const float* __restrict__ bk,
    unsigned short* __restrict__ wqk, unsigned short* __restrict__ wvb,
    unsigned short* __restrict__ wob, float* __restrict__ bqk) {
  int i = blockIdx.x * 256 + threadIdx.x;
  wqk[i]          = f2bf(wq[i]);
  wqk[262144 + i] = f2bf(wk[i]);
  wvb[i] = f2bf(wv[i]);
  wob[i] = f2bf(wo[i]);
  if (i < 512) { bqk[i] = bq[i]; bqk[512 + i] = bk[i]; }
}

// ---------------- GroupNorm stats: one block per (b,g) ----------------
__global__ __launch_bounds__(256) void gn_stats_kernel(
    const float* __restrict__ x, float* __restrict__ stats) {
  int bg = blockIdx.x;
  const float4* p = (const float4*)(x + (long)bg * 65536);
  float s = 0.f, ss = 0.f;
#pragma unroll 8
  for (int i = 0; i < 64; ++i) {
    float4 v = p[threadIdx.x + 256 * i];
    s  += v.x + v.y + v.z + v.w;
    ss += v.x*v.x + v.y*v.y + v.z*v.z + v.w*v.w;
  }
  __shared__ float red[8];
  float w1 = wave_sum(s), w2 = wave_sum(ss);
  int wave = threadIdx.x >> 6;
  if ((threadIdx.x & 63) == 0) { red[wave] = w1; red[4 + wave] = w2; }
  __syncthreads();
  if (threadIdx.x == 0) {
    float S1 = red[0] + red[1] + red[2] + red[3];
    float S2 = red[4] + red[5] + red[6] + red[7];
    float mu = S1 * (1.f / 65536.f);
    float var = S2 * (1.f / 65536.f) - mu * mu;
    stats[bg * 2]     = mu;
    stats[bg * 2 + 1] = rsqrtf(var + 1e-5f);
  }
}

// ------- GroupNorm normalize + transpose: h_t[b][n][c] bf16 ------
__global__ __launch_bounds__(256) void gn_norm_kernel(
    const float* __restrict__ x, const float* __restrict__ stats,
    const float* __restrict__ gamma, const float* __restrict__ beta,
    unsigned short* __restrict__ hout) {
  int b = blockIdx.y;
  int n0 = blockIdx.x * 128;
  int tid = threadIdx.x;
  __shared__ unsigned short lt[128][33];
  const float* xb = x + (long)b * (512L * 4096);
  unsigned short* hb = hout + (long)b * (4096L * 512);
  for (int cc0 = 0; cc0 < 512; cc0 += 32) {
#pragma unroll
    for (int i = 0; i < 4; ++i) {
      int idx = tid + 256 * i;
      int c = idx >> 5, nf = idx & 31;
      int ch = cc0 + c;
      float4 v = *(const float4*)(xb + (long)ch * 4096 + n0 + nf * 4);
      float mu = stats[(b * 32 + (ch >> 4)) * 2];
      float rs = stats[(b * 32 + (ch >> 4)) * 2 + 1];
      float ga = gamma[ch] * rs;
      float be = beta[ch] - mu * ga;
      int nl = nf * 4;
      lt[nl + 0][c] = f2bf(v.x * ga + be);
      lt[nl + 1][c] = f2bf(v.y * ga + be);
      lt[nl + 2][c] = f2bf(v.z * ga + be);
      lt[nl + 3][c] = f2bf(v.w * ga + be);
    }
    __syncthreads();
#pragma unroll
    for (int i = 0; i < 2; ++i) {
      int idx = tid + 256 * i;
      int row = idx >> 2, part = idx & 3;
      union { uint4 u; unsigned short s[8]; } o;
#pragma unroll
      for (int j = 0; j < 8; ++j) o.s[j] = lt[row][part * 8 + j];
      *(uint4*)(hb + (long)(n0 + row) * 512 + cc0 + part * 8) = o.u;
    }
    __syncthreads();
  }
}

// ---------------- NT GEMM: Out[i][j] = sum_k A[i][k]*B[j][k] -------------
#define BM 128
#define BN 128
#define BKD 64

enum { EPI_BF16 = 0, EPI_BF16_COLBIAS = 1, EPI_BF16_ROWBIAS = 2,
       EPI_F32_SCALE = 3, EPI_F32_RES = 4 };

DEVINL void stage128x64(const unsigned short* g, int ld, unsigned short* l, int tid) {
  int wave = tid >> 6;
#pragma unroll
  for (int it = 0; it < 4; ++it) {
    int seg = it * 256 + tid;
    int row = seg >> 3, ks = seg & 7;
    const unsigned short* gp = g + (long)row * ld + ks * 8;
    unsigned short* lp = l + (it * 256 + wave * 64) * 8;
    __builtin_amdgcn_global_load_lds(
        (const __attribute__((address_space(1))) void*)gp,
        (__attribute__((address_space(3))) void*)lp, 16, 0, 0);
  }
}

template <int EPI>
__global__ __launch_bounds__(256, 2) void gemm_nt(
    const unsigned short* __restrict__ A, long strideA, int lda,
    const unsigned short* __restrict__ B, long strideB, int ldb,
    void* __restrict__ C, long strideC, int ldc, int K,
    const float* __restrict__ bias, float scale,
    const float* __restrict__ resid, long strideR) {
  __shared__ __align__(16) unsigned short lA[BM * BKD];
  __shared__ __align__(16) unsigned short lB[BN * BKD];
  int z = blockIdx.z;
  const unsigned short* Ab = A + (long)z * strideA + (long)blockIdx.y * BM * lda;
  const unsigned short* Bb = B + (long)z * strideB + (long)blockIdx.x * BN * ldb;
  int tid = threadIdx.x;
  int lane = tid & 63, wave = tid >> 6;
  int wm = (wave >> 1) * 64, wn = (wave & 1) * 64;
  int lr = lane & 15;
  int lk = (lane >> 4) * 8;

  f32x4 acc[4][4];
#pragma unroll
  for (int i = 0; i < 4; ++i)
#pragma unroll
    for (int j = 0; j < 4; ++j) acc[i][j] = (f32x4){0.f, 0.f, 0.f, 0.f};

  for (int k0 = 0; k0 < K; k0 += BKD) {
    __syncthreads();
    stage128x64(Ab + k0, lda, lA, tid);
    stage128x64(Bb + k0, ldb, lB, tid);
    __syncthreads();
#pragma unroll
    for (int kk = 0; kk < 2; ++kk) {
      s16x8 af[4], bfr[4];
#pragma unroll
      for (int i = 0; i < 4; ++i)
        af[i] = *(const s16x8*)&lA[(wm + i * 16 + lr) * BKD + kk * 32 + lk];
#pragma unroll
      for (int i = 0; i < 4; ++i)
        bfr[i] = *(const s16x8*)&lB[(wn + i * 16 + lr) * BKD + kk * 32 + lk];
#pragma unroll
      for (int mi = 0; mi < 4; ++mi)
#pragma unroll
        for (int ni = 0; ni < 4; ++ni)
          acc[mi][ni] = __builtin_amdgcn_mfma_f32_16x16x32_bf16(
              af[mi], bfr[ni], acc[mi][ni], 0, 0, 0);
    }
  }

  int rbase = blockIdx.y * BM + wm + (lane >> 4) * 4;
  int cbase = blockIdx.x * BN + wn + lr;
  long cb = (long)z * strideC;
#pragma unroll
  for (int mi = 0; mi < 4; ++mi) {
#pragma unroll
    for (int ni = 0; ni < 4; ++ni) {
      int col = cbase + ni * 16;
#pragma unroll
      for (int r = 0; r < 4; ++r) {
        int row = rbase + mi * 16 + r;
        float val = acc[mi][ni][r];
        long off = cb + (long)row * ldc + col;
        if constexpr (EPI == EPI_BF16) {
          ((unsigned short*)C)[off] = f2bf(val);
        } else if constexpr (EPI == EPI_BF16_COLBIAS) {
          ((unsigned short*)C)[off] = f2bf(val + bias[col]);
        } else if constexpr (EPI == EPI_BF16_ROWBIAS) {
          ((unsigned short*)C)[off] = f2bf(val + bias[row]);
        } else if constexpr (EPI == EPI_F32_SCALE) {
          ((float*)C)[off] = val * scale;
        } else {
          ((float*)C)[off] =
              val + bias[row] + resid[(long)z * strideR + (long)row * ldc + col];
        }
      }
    }
  }
}

// ---------------- fused flash attention ----------------
// grid 256: block = (batch = bid&7, qblock = bid>>3). 512 threads = 8 waves.
// Wave w owns q-rows qb*128 + w*16 .. +15. KV tiles of 64, full D=512.
// qk: [8][4096][1024] bf16 (Q cols 0..511, K cols 512..1023)
// v:  [8][512][4096] bf16 (c-major)   o: [8][4096][512] bf16
__global__ __launch_bounds__(512, 2) void flash_kernel(
    const unsigned short* __restrict__ qk, const unsigned short* __restrict__ v,
    unsigned short* __restrict__ o, float scale) {
  __shared__ __align__(16) unsigned short lK[64 * 512];   // 64 KB (swizzled)
  __shared__ __align__(16) unsigned short lV[512 * 64];   // 64 KB (swizzled)
  __shared__ __align__(16) unsigned short lP[8 * 16 * 64];// 16 KB

  int bid = blockIdx.x;
  int b = bid & 7, qb = bid >> 3;                // batch->XCD affinity
  const unsigned short* qkb = qk + (long)b * 4096 * 1024;
  const unsigned short* vb  = v  + (long)b * 512 * 4096;
  int tid = threadIdx.x, lane = tid & 63, wv = tid >> 6;
  int g = lane >> 4, qi = lane & 15;
  int swz = (qi & 7) << 4;                       // read-side byte swizzle
  int q0 = qb * 128 + wv * 16;

  // Q B-frags (persistent): qf[kk] = Q[q0+qi][kk*32 + g*8 .. +7]
  s16x8 qf[16];
  {
    const unsigned short* qrow = qkb + (long)(q0 + qi) * 1024 + g * 8;
#pragma unroll
    for (int kk = 0; kk < 16; ++kk)
      qf[kk] = *(const s16x8*)(qrow + kk * 32);
  }

  f32x4 accO[32];
#pragma unroll
  for (int i = 0; i < 32; ++i) accO[i] = (f32x4){0.f, 0.f, 0.f, 0.f};
  float m_run = -3.0e38f, l_run = 0.f;

  unsigned short* pw = lP + wv * 1024;           // this wave's P region

  for (int t = 0; t < 64; ++t) {
    int kv0 = t * 64;
    __syncthreads();  // all waves done reading previous tile
    // stage K-tile [64 kv][512 k], source pre-swizzled so reads can XOR
#pragma unroll
    for (int it = 0; it < 8; ++it) {
      int s = it * 512 + tid;
      int row = s >> 6;
      int ks = (s & 63) ^ (row & 7);
      const unsigned short* gp = qkb + (long)(kv0 + row) * 1024 + 512 + ks * 8;
      unsigned short* lp = lK + (it * 512 + wv * 64) * 8;
      __builtin_amdgcn_global_load_lds(
          (const __attribute__((address_space(1))) void*)gp,
          (__attribute__((address_space(3))) void*)lp, 16, 0, 0);
    }
    // stage V-tile [512 c][64 kv]
#pragma unroll
    for (int it = 0; it < 8; ++it) {
      int s = it * 512 + tid;
      int row = s >> 3;
      int ks = (s & 7) ^ (row & 7);
      const unsigned short* gp = vb + (long)row * 4096 + kv0 + ks * 8;
      unsigned short* lp = lV + (it * 512 + wv * 64) * 8;
      __builtin_amdgcn_global_load_lds(
          (const __attribute__((address_space(1))) void*)gp,
          (__attribute__((address_space(3))) void*)lp, 16, 0, 0);
    }
    __syncthreads();  // staged data visible

    // --- QK^T (swapped): sacc[n] = S^T tile, lane holds S^T[n*16+g*4+r][qi]
    f32x4 sacc[4];
#pragma unroll
    for (int n = 0; n < 4; ++n) sacc[n] = (f32x4){0.f, 0.f, 0.f, 0.f};
#pragma unroll
    for (int kk = 0; kk < 16; ++kk) {
      int koff = (kk * 64 + g * 16) ^ swz;
#pragma unroll
      for (int n = 0; n < 4; ++n) {
        int row = n * 16 + qi;
        s16x8 kf = *(const s16x8*)((const char*)lK + row * 1024 + koff);
        sacc[n] = __builtin_amdgcn_mfma_f32_16x16x32_bf16(kf, qf[kk], sacc[n], 0, 0, 0);
      }
    }

    // --- online softmax for q = qi (this lane's column)
    float mx = -3.0e38f;
#pragma unroll
    for (int n = 0; n < 4; ++n)
#pragma unroll
      for (int r = 0; r < 4; ++r) {
        sacc[n][r] *= scale;
        mx = fmaxf(mx, sacc[n][r]);
      }
    mx = fmaxf(mx, __shfl_xor(mx, 16, 64));
    mx = fmaxf(mx, __shfl_xor(mx, 32, 64));
    float m_new = fmaxf(m_run, mx);
    float corr = __expf(m_run - m_new);
    float rowsum = 0.f;
#pragma unroll
    for (int n = 0; n < 4; ++n)
#pragma unroll
      for (int r = 0; r < 4; ++r) {
        float p = __expf(sacc[n][r] - m_new);
        sacc[n][r] = p;
        rowsum += p;
      }
    rowsum += __shfl_xor(rowsum, 16, 64);
    rowsum += __shfl_xor(rowsum, 32, 64);
    l_run = l_run * corr + rowsum;
    m_run = m_new;

    // rescale O (rows q = g*4+r need corr from lane g*4+r)
    float corr_o[4];
#pragma unroll
    for (int r = 0; r < 4; ++r) corr_o[r] = __shfl(corr, g * 4 + r, 64);
#pragma unroll
    for (int ct = 0; ct < 32; ++ct)
#pragma unroll
      for (int r = 0; r < 4; ++r) accO[ct][r] *= corr_o[r];

    // --- write P[q=qi][kv] to LDS (bf16, swizzled), per-wave private
#pragma unroll
    for (int n = 0; n < 4; ++n) {
      uint2 pk;
      pk.x = (unsigned)f2bf(sacc[n][0]) | ((unsigned)f2bf(sacc[n][1]) << 16);
      pk.y = (unsigned)f2bf(sacc[n][2]) | ((unsigned)f2bf(sacc[n][3]) << 16);
      *(uint2*)((char*)pw + qi * 128 + ((n * 32 + g * 8) ^ swz)) = pk;
    }

    // --- PV: accO[ct] += P[16q x 64kv] * V[ct-tile][64kv]
#pragma unroll
    for (int kk2 = 0; kk2 < 2; ++kk2) {
      s16x8 paf = *(const s16x8*)((const char*)pw + qi * 128 + ((kk2 * 64 + g * 16) ^ swz));
      int voff = (kk2 * 64 + g * 16) ^ swz;
#pragma unroll
      for (int ct = 0; ct < 32; ++ct) {
        int row = ct * 16 + qi;
        s16x8 vf = *(const s16x8*)((const char*)lV + row * 128 + voff);
        accO[ct] = __builtin_amdgcn_mfma_f32_16x16x32_bf16(paf, vf, accO[ct], 0, 0, 0);
      }
    }
  }

  // epilogue: O /= l, write o[q0+g*4+r][ct*16+qi]
  float linv = 1.0f / l_run;
  float linv_o[4];
#pragma unroll
  for (int r = 0; r < 4; ++r) linv_o[r] = __shfl(linv, g * 4 + r, 64);
  unsigned short* ob = o + (long)b * (4096L * 512) + (long)q0 * 512;
#pragma unroll
  for (int ct = 0; ct < 32; ++ct)
#pragma unroll
    for (int r = 0; r < 4; ++r)
      ob[(g * 4 + r) * 512 + ct * 16 + qi] = f2bf(accO[ct][r] * linv_o[r]);
}

// ---------------- launcher ----------------
extern "C" void kernel_launch(void* const* d_in, const int* in_sizes, int n_in,
                              void* d_out, int out_size, void* d_ws, size_t ws_size,
                              hipStream_t stream) {
  const float* x   = (const float*)d_in[0];
  const float* gsc = (const float*)d_in[1];
  const float* gbi = (const float*)d_in[2];
  const float* wq  = (const float*)d_in[3];
  const float* bq  = (const float*)d_in[4];
  const float* wk  = (const float*)d_in[5];
  const float* bk  = (const float*)d_in[6];
  const float* wv  = (const float*)d_in[7];
  const float* bv  = (const float*)d_in[8];
  const float* wo  = (const float*)d_in[9];
  const float* bo  = (const float*)d_in[10];
  float* out = (float*)d_out;

  // fixed region (~2.1 MB), then big buffers at 4 MiB (total 164 MB; ws >= 214 MB)
  char* w = (char*)d_ws;
  unsigned short* wqk  = (unsigned short*)(w);
  unsigned short* wvb  = (unsigned short*)(w + 1048576);
  unsigned short* wob  = (unsigned short*)(w + 1572864);
  float*          bqk  = (float*)(w + 2097152);
  float*          stats= (float*)(w + 2101248);
  char* big = w + 4194304;
  unsigned short* h_t  = (unsigned short*)(big);               // 33,554,432
  unsigned short* qkb  = (unsigned short*)(big + 33554432);    // 67,108,864
  unsigned short* vbuf = (unsigned short*)(big + 100663296);   // 33,554,432
  unsigned short* o_t  = (unsigned short*)(big + 134217728);   // 33,554,432

  prep_kernel<<<1024, 256, 0, stream>>>(wq, wk, wv, wo, bq, bk, wqk, wvb, wob, bqk);
  gn_stats_kernel<<<256, 256, 0, stream>>>(x, stats);
  gn_norm_kernel<<<dim3(32, 8), 256, 0, stream>>>(x, stats, gsc, gbi, h_t);

  const float scale = 0.04419417382415922f;   // 512^-0.5
  const long HB = 4096L * 512;
  const long XB = 512L * 4096;

  // QK projection: qkb[b][n][j] = sum_c h_t[b][n][c] * wqk[j][c] + bqk[j]
  gemm_nt<EPI_BF16_COLBIAS><<<dim3(8, 32, 8), 256, 0, stream>>>(
      h_t, HB, 512, wqk, 0, 512, qkb, 4096L * 1024, 1024, 512, bqk, 1.f, nullptr, 0);
  // V projection: vbuf[b][c][n] = sum_k wvb[c][k] * h_t[b][n][k] + bv[c]
  gemm_nt<EPI_BF16_ROWBIAS><<<dim3(32, 4, 8), 256, 0, stream>>>(
      wvb, 0, 512, h_t, HB, 512, vbuf, XB, 4096, 512, bv, 1.f, nullptr, 0);

  // fused attention: o_t[b][n][c]
  flash_kernel<<<256, 512, 0, stream>>>(qkb, vbuf, o_t, scale);

  // out: out[b][m][n] = x + bo[m] + sum_c wob[m][c] * o_t[b][n][c]
  gemm_nt<EPI_F32_RES><<<dim3(32, 4, 8), 256, 0, stream>>>(
      wob, 0, 512, o_t, HB, 512, out, XB, 4096, 512, bo, 1.f, x, XB);
}

// Round 4
// 774.427 us; speedup vs baseline: 1.7918x; 1.6928x over previous
//
#include <hip/hip_runtime.h>

#define DEVINL __device__ __forceinline__

typedef __attribute__((ext_vector_type(8))) short s16x8;
typedef __attribute__((ext_vector_type(4))) float f32x4;

DEVINL unsigned short f2bf(float f) {
  union { float f; unsigned u; } v; v.f = f;
  unsigned r = v.u + 0x7FFFu + ((v.u >> 16) & 1u);
  return (unsigned short)(r >> 16);
}

DEVINL float wave_sum(float v) {
#pragma unroll
  for (int o = 32; o > 0; o >>= 1) v += __shfl_xor(v, o, 64);
  return v;
}

// ---------------- weight prep: fp32 -> bf16, stack wq|wk ----------------
__global__ __launch_bounds__(256) void prep_kernel(
    const float* __restrict__ wq, const float* __restrict__ wk,
    const float* __restrict__ wv, const float* __restrict__ wo,
    const float* __restrict__ bq, const float* __restrict__ bk,
    unsigned short* __restrict__ wqk, unsigned short* __restrict__ wvb,
    unsigned short* __restrict__ wob, float* __restrict__ bqk) {
  int i = blockIdx.x * 256 + threadIdx.x;
  wqk[i]          = f2bf(wq[i]);
  wqk[262144 + i] = f2bf(wk[i]);
  wvb[i] = f2bf(wv[i]);
  wob[i] = f2bf(wo[i]);
  if (i < 512) { bqk[i] = bq[i]; bqk[512 + i] = bk[i]; }
}

// ---------------- GroupNorm stats: one block per (b,g) ----------------
__global__ __launch_bounds__(256) void gn_stats_kernel(
    const float* __restrict__ x, float* __restrict__ stats) {
  int bg = blockIdx.x;
  const float4* p = (const float4*)(x + (long)bg * 65536);
  float s = 0.f, ss = 0.f;
#pragma unroll 8
  for (int i = 0; i < 64; ++i) {
    float4 v = p[threadIdx.x + 256 * i];
    s  += v.x + v.y + v.z + v.w;
    ss += v.x*v.x + v.y*v.y + v.z*v.z + v.w*v.w;
  }
  __shared__ float red[8];
  float w1 = wave_sum(s), w2 = wave_sum(ss);
  int wave = threadIdx.x >> 6;
  if ((threadIdx.x & 63) == 0) { red[wave] = w1; red[4 + wave] = w2; }
  __syncthreads();
  if (threadIdx.x == 0) {
    float S1 = red[0] + red[1] + red[2] + red[3];
    float S2 = red[4] + red[5] + red[6] + red[7];
    float mu = S1 * (1.f / 65536.f);
    float var = S2 * (1.f / 65536.f) - mu * mu;
    stats[bg * 2]     = mu;
    stats[bg * 2 + 1] = rsqrtf(var + 1e-5f);
  }
}

// ------- GroupNorm normalize + transpose: h_t[b][n][c] bf16 ------
__global__ __launch_bounds__(256) void gn_norm_kernel(
    const float* __restrict__ x, const float* __restrict__ stats,
    const float* __restrict__ gamma, const float* __restrict__ beta,
    unsigned short* __restrict__ hout) {
  int b = blockIdx.y;
  int n0 = blockIdx.x * 128;
  int tid = threadIdx.x;
  __shared__ unsigned short lt[128][33];
  const float* xb = x + (long)b * (512L * 4096);
  unsigned short* hb = hout + (long)b * (4096L * 512);
  for (int cc0 = 0; cc0 < 512; cc0 += 32) {
#pragma unroll
    for (int i = 0; i < 4; ++i) {
      int idx = tid + 256 * i;
      int c = idx >> 5, nf = idx & 31;
      int ch = cc0 + c;
      float4 v = *(const float4*)(xb + (long)ch * 4096 + n0 + nf * 4);
      float mu = stats[(b * 32 + (ch >> 4)) * 2];
      float rs = stats[(b * 32 + (ch >> 4)) * 2 + 1];
      float ga = gamma[ch] * rs;
      float be = beta[ch] - mu * ga;
      int nl = nf * 4;
      lt[nl + 0][c] = f2bf(v.x * ga + be);
      lt[nl + 1][c] = f2bf(v.y * ga + be);
      lt[nl + 2][c] = f2bf(v.z * ga + be);
      lt[nl + 3][c] = f2bf(v.w * ga + be);
    }
    __syncthreads();
#pragma unroll
    for (int i = 0; i < 2; ++i) {
      int idx = tid + 256 * i;
      int row = idx >> 2, part = idx & 3;
      union { uint4 u; unsigned short s[8]; } o;
#pragma unroll
      for (int j = 0; j < 8; ++j) o.s[j] = lt[row][part * 8 + j];
      *(uint4*)(hb + (long)(n0 + row) * 512 + cc0 + part * 8) = o.u;
    }
    __syncthreads();
  }
}

// ---------------- NT GEMM: Out[i][j] = sum_k A[i][k]*B[j][k] -------------
#define BM 128
#define BN 128
#define BKD 64

enum { EPI_BF16 = 0, EPI_BF16_COLBIAS = 1, EPI_BF16_ROWBIAS = 2,
       EPI_F32_SCALE = 3, EPI_F32_RES = 4 };

DEVINL void stage128x64(const unsigned short* g, int ld, unsigned short* l, int tid) {
  int wave = tid >> 6;
#pragma unroll
  for (int it = 0; it < 4; ++it) {
    int seg = it * 256 + tid;
    int row = seg >> 3, ks = seg & 7;
    const unsigned short* gp = g + (long)row * ld + ks * 8;
    unsigned short* lp = l + (it * 256 + wave * 64) * 8;
    __builtin_amdgcn_global_load_lds(
        (const __attribute__((address_space(1))) void*)gp,
        (__attribute__((address_space(3))) void*)lp, 16, 0, 0);
  }
}

template <int EPI>
__global__ __launch_bounds__(256, 2) void gemm_nt(
    const unsigned short* __restrict__ A, long strideA, int lda,
    const unsigned short* __restrict__ B, long strideB, int ldb,
    void* __restrict__ C, long strideC, int ldc, int K,
    const float* __restrict__ bias, float scale,
    const float* __restrict__ resid, long strideR) {
  __shared__ __align__(16) unsigned short lA[BM * BKD];
  __shared__ __align__(16) unsigned short lB[BN * BKD];
  int z = blockIdx.z;
  const unsigned short* Ab = A + (long)z * strideA + (long)blockIdx.y * BM * lda;
  const unsigned short* Bb = B + (long)z * strideB + (long)blockIdx.x * BN * ldb;
  int tid = threadIdx.x;
  int lane = tid & 63, wave = tid >> 6;
  int wm = (wave >> 1) * 64, wn = (wave & 1) * 64;
  int lr = lane & 15;
  int lk = (lane >> 4) * 8;

  f32x4 acc[4][4];
#pragma unroll
  for (int i = 0; i < 4; ++i)
#pragma unroll
    for (int j = 0; j < 4; ++j) acc[i][j] = (f32x4){0.f, 0.f, 0.f, 0.f};

  for (int k0 = 0; k0 < K; k0 += BKD) {
    __syncthreads();
    stage128x64(Ab + k0, lda, lA, tid);
    stage128x64(Bb + k0, ldb, lB, tid);
    __syncthreads();
#pragma unroll
    for (int kk = 0; kk < 2; ++kk) {
      s16x8 af[4], bfr[4];
#pragma unroll
      for (int i = 0; i < 4; ++i)
        af[i] = *(const s16x8*)&lA[(wm + i * 16 + lr) * BKD + kk * 32 + lk];
#pragma unroll
      for (int i = 0; i < 4; ++i)
        bfr[i] = *(const s16x8*)&lB[(wn + i * 16 + lr) * BKD + kk * 32 + lk];
#pragma unroll
      for (int mi = 0; mi < 4; ++mi)
#pragma unroll
        for (int ni = 0; ni < 4; ++ni)
          acc[mi][ni] = __builtin_amdgcn_mfma_f32_16x16x32_bf16(
              af[mi], bfr[ni], acc[mi][ni], 0, 0, 0);
    }
  }

  int rbase = blockIdx.y * BM + wm + (lane >> 4) * 4;
  int cbase = blockIdx.x * BN + wn + lr;
  long cb = (long)z * strideC;
#pragma unroll
  for (int mi = 0; mi < 4; ++mi) {
#pragma unroll
    for (int ni = 0; ni < 4; ++ni) {
      int col = cbase + ni * 16;
#pragma unroll
      for (int r = 0; r < 4; ++r) {
        int row = rbase + mi * 16 + r;
        float val = acc[mi][ni][r];
        long off = cb + (long)row * ldc + col;
        if constexpr (EPI == EPI_BF16) {
          ((unsigned short*)C)[off] = f2bf(val);
        } else if constexpr (EPI == EPI_BF16_COLBIAS) {
          ((unsigned short*)C)[off] = f2bf(val + bias[col]);
        } else if constexpr (EPI == EPI_BF16_ROWBIAS) {
          ((unsigned short*)C)[off] = f2bf(val + bias[row]);
        } else if constexpr (EPI == EPI_F32_SCALE) {
          ((float*)C)[off] = val * scale;
        } else {
          ((float*)C)[off] =
              val + bias[row] + resid[(long)z * strideR + (long)row * ldc + col];
        }
      }
    }
  }
}

// ---------------- fused flash attention v2 (double-buffered) ----------------
// grid 256: b = bid&7, qb = bid>>3. 512 threads = 8 waves.
// QK phase: wave w owns q-rows qb*128 + w*16..+15 (as r3, KVBLK=32 now).
// PV phase: wave grid 2x4: wave owns O[64q x 128c].
// Pipeline per tile: stageK(t+1) | QK+softmax+P -> barrier -> stageV(t+1) | PV -> barrier.
DEVINL void stage_k32(const unsigned short* qkb, unsigned short* dst,
                      int kv0, int tid, int wv) {
#pragma unroll
  for (int it = 0; it < 4; ++it) {
    int s = it * 512 + tid;
    int row = s >> 6, c16 = s & 63;
    const unsigned short* gp = qkb + (long)(kv0 + row) * 1024 + 512 + ((c16 ^ (row & 7)) * 8);
    unsigned short* lp = dst + (it * 512 + wv * 64) * 8;
    __builtin_amdgcn_global_load_lds(
        (const __attribute__((address_space(1))) void*)gp,
        (__attribute__((address_space(3))) void*)lp, 16, 0, 0);
  }
}

DEVINL void stage_v32(const unsigned short* vbb, unsigned short* dst,
                      int kv0, int tid, int wv) {
#pragma unroll
  for (int it = 0; it < 4; ++it) {
    int s = it * 512 + tid;
    int c = s >> 2, ks = s & 3;
    const unsigned short* gp = vbb + (long)c * 4096 + kv0 + ((ks ^ ((c >> 1) & 3)) * 8);
    unsigned short* lp = dst + (it * 512 + wv * 64) * 8;
    __builtin_amdgcn_global_load_lds(
        (const __attribute__((address_space(1))) void*)gp,
        (__attribute__((address_space(3))) void*)lp, 16, 0, 0);
  }
}

__global__ __launch_bounds__(512, 2) void flash2_kernel(
    const unsigned short* __restrict__ qk, const unsigned short* __restrict__ v,
    unsigned short* __restrict__ o, float scale) {
  __shared__ __align__(16) unsigned short lK[2][32 * 512];   // 2 x 32 KB
  __shared__ __align__(16) unsigned short lV[2][512 * 32];   // 2 x 32 KB
  __shared__ __align__(16) unsigned short lP[128 * 64];      // 16 KB (swizzled)
  __shared__ float lCorr[128];

  int bid = blockIdx.x;
  int b = bid & 7, qb = bid >> 3;
  const unsigned short* qkb = qk + (long)b * 4096 * 1024;
  const unsigned short* vb  = v  + (long)b * 512 * 4096;
  int tid = threadIdx.x, lane = tid & 63, wv = tid >> 6;
  int g = lane >> 4, qi = lane & 15;
  int q0 = qb * 128;
  int wq = wv >> 2, wc = wv & 3;     // PV wave grid 2x4

  // persistent Q B-frags: qf[kk] = Q[q0+wv*16+qi][kk*32 + g*8 .. +7]
  s16x8 qf[16];
  {
    const unsigned short* qrow = qkb + (long)(q0 + wv * 16 + qi) * 1024 + g * 8;
#pragma unroll
    for (int kk = 0; kk < 16; ++kk) qf[kk] = *(const s16x8*)(qrow + kk * 32);
  }

  f32x4 accO[4][8];
#pragma unroll
  for (int i = 0; i < 4; ++i)
#pragma unroll
    for (int j = 0; j < 8; ++j) accO[i][j] = (f32x4){0.f, 0.f, 0.f, 0.f};
  float m_run = -3.0e38f, l_run = 0.f;

  stage_k32(qkb, &lK[0][0], 0, tid, wv);
  stage_v32(vb, &lV[0][0], 0, tid, wv);
  __syncthreads();

  int cur = 0;
  for (int t = 0; t < 128; ++t) {
    int nxt = t < 127 ? t + 1 : 127;
    // ---- phase 1: prefetch K(t+1); QK^T + softmax + P write on buf cur ----
    stage_k32(qkb, &lK[cur ^ 1][0], nxt * 32, tid, wv);

    f32x4 sacc[2];
    sacc[0] = (f32x4){0.f, 0.f, 0.f, 0.f};
    sacc[1] = (f32x4){0.f, 0.f, 0.f, 0.f};
    const char* lkc = (const char*)&lK[cur][0];
#pragma unroll
    for (int kk = 0; kk < 16; ++kk) {
      int ko = (kk * 64 + g * 16) ^ ((qi & 7) << 4);
#pragma unroll
      for (int sub = 0; sub < 2; ++sub) {
        const s16x8 kf = *(const s16x8*)(lkc + (sub * 16 + qi) * 1024 + ko);
        sacc[sub] = __builtin_amdgcn_mfma_f32_16x16x32_bf16(kf, qf[kk], sacc[sub], 0, 0, 0);
      }
    }
    // online softmax: lane owns q-col (wv*16+qi), 8 kv values
    float mx = -3.0e38f;
#pragma unroll
    for (int sub = 0; sub < 2; ++sub)
#pragma unroll
      for (int r = 0; r < 4; ++r) { sacc[sub][r] *= scale; mx = fmaxf(mx, sacc[sub][r]); }
    mx = fmaxf(mx, __shfl_xor(mx, 16, 64));
    mx = fmaxf(mx, __shfl_xor(mx, 32, 64));
    float m_new = fmaxf(m_run, mx);
    float corr = __expf(m_run - m_new);
    float rowsum = 0.f;
#pragma unroll
    for (int sub = 0; sub < 2; ++sub)
#pragma unroll
      for (int r = 0; r < 4; ++r) {
        float p = __expf(sacc[sub][r] - m_new);
        sacc[sub][r] = p;
        rowsum += p;
      }
    rowsum += __shfl_xor(rowsum, 16, 64);
    rowsum += __shfl_xor(rowsum, 32, 64);
    l_run = l_run * corr + rowsum;
    m_run = m_new;
    if (g == 0) lCorr[wv * 16 + qi] = corr;
    {
      int q = wv * 16 + qi;
#pragma unroll
      for (int sub = 0; sub < 2; ++sub) {
        uint2 pk;
        pk.x = (unsigned)f2bf(sacc[sub][0]) | ((unsigned)f2bf(sacc[sub][1]) << 16);
        pk.y = (unsigned)f2bf(sacc[sub][2]) | ((unsigned)f2bf(sacc[sub][3]) << 16);
        int chunk = (sub * 2 + (g >> 1)) ^ (q & 7);
        *(uint2*)((char*)lP + q * 128 + (chunk << 4) + (g & 1) * 8) = pk;
      }
    }
    __syncthreads();   // P/corr visible; K(t+1) drained (auto vmcnt0)

    // ---- phase 2: prefetch V(t+1); rescale O; PV on buf cur ----
    stage_v32(vb, &lV[cur ^ 1][0], nxt * 32, tid, wv);
#pragma unroll
    for (int i = 0; i < 4; ++i) {
      f32x4 cr = *(const f32x4*)&lCorr[wq * 64 + i * 16 + g * 4];
#pragma unroll
      for (int j = 0; j < 8; ++j)
#pragma unroll
        for (int r = 0; r < 4; ++r) accO[i][j][r] *= cr[r];
    }
    const char* lvc = (const char*)&lV[cur][0];
#pragma unroll
    for (int jg = 0; jg < 2; ++jg) {
      s16x8 vf[4];
#pragma unroll
      for (int j2 = 0; j2 < 4; ++j2) {
        int c = (wc * 8 + jg * 4 + j2) * 16 + qi;
        vf[j2] = *(const s16x8*)(lvc + c * 64 + ((g ^ ((qi >> 1) & 3)) << 4));
      }
#pragma unroll
      for (int i = 0; i < 4; ++i) {
        int q = (wq * 4 + i) * 16 + qi;
        const s16x8 pf = *(const s16x8*)((const char*)lP + q * 128 + ((g ^ (q & 7)) << 4));
#pragma unroll
        for (int j2 = 0; j2 < 4; ++j2)
          accO[i][jg * 4 + j2] = __builtin_amdgcn_mfma_f32_16x16x32_bf16(
              pf, vf[j2], accO[i][jg * 4 + j2], 0, 0, 0);
      }
    }
    __syncthreads();   // PV done; V(t+1) drained
    cur ^= 1;
  }

  // epilogue: distribute 1/l via LDS, scale, store o[b][q][c]
  if (g == 0) lCorr[wv * 16 + qi] = 1.0f / l_run;
  __syncthreads();
  unsigned short* ob = o + (long)b * (4096L * 512) + (long)q0 * 512;
#pragma unroll
  for (int i = 0; i < 4; ++i) {
    f32x4 fr = *(const f32x4*)&lCorr[wq * 64 + i * 16 + g * 4];
#pragma unroll
    for (int j = 0; j < 8; ++j)
#pragma unroll
      for (int r = 0; r < 4; ++r)
        ob[(long)(wq * 64 + i * 16 + g * 4 + r) * 512 + wc * 128 + j * 16 + qi] =
            f2bf(accO[i][j][r] * fr[r]);
  }
}

// ---------------- launcher ----------------
extern "C" void kernel_launch(void* const* d_in, const int* in_sizes, int n_in,
                              void* d_out, int out_size, void* d_ws, size_t ws_size,
                              hipStream_t stream) {
  const float* x   = (const float*)d_in[0];
  const float* gsc = (const float*)d_in[1];
  const float* gbi = (const float*)d_in[2];
  const float* wq  = (const float*)d_in[3];
  const float* bq  = (const float*)d_in[4];
  const float* wk  = (const float*)d_in[5];
  const float* bk  = (const float*)d_in[6];
  const float* wv  = (const float*)d_in[7];
  const float* bv  = (const float*)d_in[8];
  const float* wo  = (const float*)d_in[9];
  const float* bo  = (const float*)d_in[10];
  float* out = (float*)d_out;

  char* w = (char*)d_ws;
  unsigned short* wqk  = (unsigned short*)(w);
  unsigned short* wvb  = (unsigned short*)(w + 1048576);
  unsigned short* wob  = (unsigned short*)(w + 1572864);
  float*          bqk  = (float*)(w + 2097152);
  float*          stats= (float*)(w + 2101248);
  char* big = w + 4194304;
  unsigned short* h_t  = (unsigned short*)(big);               // 33,554,432
  unsigned short* qkb  = (unsigned short*)(big + 33554432);    // 67,108,864
  unsigned short* vbuf = (unsigned short*)(big + 100663296);   // 33,554,432
  unsigned short* o_t  = (unsigned short*)(big + 134217728);   // 33,554,432

  prep_kernel<<<1024, 256, 0, stream>>>(wq, wk, wv, wo, bq, bk, wqk, wvb, wob, bqk);
  gn_stats_kernel<<<256, 256, 0, stream>>>(x, stats);
  gn_norm_kernel<<<dim3(32, 8), 256, 0, stream>>>(x, stats, gsc, gbi, h_t);

  const float scale = 0.04419417382415922f;   // 512^-0.5
  const long HB = 4096L * 512;
  const long XB = 512L * 4096;

  gemm_nt<EPI_BF16_COLBIAS><<<dim3(8, 32, 8), 256, 0, stream>>>(
      h_t, HB, 512, wqk, 0, 512, qkb, 4096L * 1024, 1024, 512, bqk, 1.f, nullptr, 0);
  gemm_nt<EPI_BF16_ROWBIAS><<<dim3(32, 4, 8), 256, 0, stream>>>(
      wvb, 0, 512, h_t, HB, 512, vbuf, XB, 4096, 512, bv, 1.f, nullptr, 0);

  flash2_kernel<<<256, 512, 0, stream>>>(qkb, vbuf, o_t, scale);

  gemm_nt<EPI_F32_RES><<<dim3(32, 4, 8), 256, 0, stream>>>(
      wob, 0, 512, o_t, HB, 512, out, XB, 4096, 512, bo, 1.f, x, XB);
}